// Round 10
// baseline (58.239 us; speedup 1.0000x reference)
//
#include <hip/hip_runtime.h>
#include <hip/hip_fp16.h>

#define B_ 2
#define C_ 64
#define H_ 192
#define W_ 384
#define K_ 8
constexpr int HW_ = H_ * W_;
constexpr int CHW_ = C_ * HW_;
constexpr int NP_ = B_ * HW_;           // 147456
constexpr int NBLK_ = NP_ / 64;         // 2304, %8==0
// ws: ft fp16 NHWC [NP][64] then trip fp32 [24][NP]
constexpr size_t FT_BYTES_ = (size_t)NP_ * 64 * sizeof(unsigned short);   // 18.9 MB
constexpr size_t WS_NEED_ = FT_BYTES_ + (size_t)24 * NP_ * sizeof(float); // 33.0 MB

static __device__ __forceinline__ __half2 u2h(uint u) {
  union { uint u; __half2 h; } x; x.u = u; return x.h;
}
static __device__ __forceinline__ uint h2u(__half2 h) {
  union { uint u; __half2 h; } x; x.h = h; return x.u;
}

// ====== K1: transpose (fp16 NHWC) + conv + softmax + triple write ======
// block = 256 thr = 4 waves, 64 pixels. LDS: stag [64][65] f32 + pr [24][2][64] f32.
__global__ __launch_bounds__(256) void prep_kernel(
    const float* __restrict__ feat, const int* __restrict__ mask,
    const float* __restrict__ Wo, const float* __restrict__ bo,
    const float* __restrict__ Ww, const float* __restrict__ bw,
    unsigned short* __restrict__ ft, float* __restrict__ trip) {
  __shared__ float lds[4160 + 3072];   // 28928 B
  float* stag = lds;
  float* pr = lds + 4160;

  const int tid = threadIdx.x;
  const int lane = tid & 63;
  const int wv = tid >> 6;
  const int p0 = blockIdx.x * 64;
  const int b = p0 / HW_;
  const int hw0 = p0 - b * HW_;
  const float* fb = feat + (size_t)b * CHW_;

  // loads feed BOTH the transpose staging and the conv partials
  float pacc[24];
#pragma unroll
  for (int j = 0; j < 24; ++j) pacc[j] = 0.f;
#pragma unroll
  for (int cc = 0; cc < 16; ++cc) {
    const int c = wv * 16 + cc;                       // wave-uniform -> s_load weights
    const float v = fb[(size_t)c * HW_ + hw0 + lane]; // coalesced 256B
    stag[lane * 65 + c] = v;
#pragma unroll
    for (int j = 0; j < 16; ++j) pacc[j] = fmaf(Wo[j * C_ + c], v, pacc[j]);
#pragma unroll
    for (int j = 0; j < 8; ++j) pacc[16 + j] = fmaf(Ww[j * C_ + c], v, pacc[16 + j]);
  }
  if (wv < 2) {
#pragma unroll
    for (int j = 0; j < 24; ++j) pr[j * 128 + wv * 64 + lane] = pacc[j];
  }
  __syncthreads();   // b1: staging + pr slots(w0,w1) ready

  // NHWC fp16 write (reads staging; disjoint from pr)
  uint* ft32 = (uint*)ft;
#pragma unroll
  for (int j = 0; j < 8; ++j) {
    const int idx = j * 256 + tid;
    const int row = idx >> 5;            // pixel 0..63
    const int cp = idx & 31;             // channel pair
    const __half2 h = __floats2half2_rn(stag[row * 65 + 2 * cp],
                                        stag[row * 65 + 2 * cp + 1]);
    ft32[(size_t)(p0 + row) * 32 + cp] = h2u(h);
  }
  if (wv >= 2) {     // fold w2->slot0, w3->slot1 (disjoint from staging reads)
    const int base = (wv - 2) * 64;
#pragma unroll
    for (int j = 0; j < 24; ++j) pr[j * 128 + base + lane] += pacc[j];
  }
  __syncthreads();   // b2: pr final

  // every wave: final reduce for its lane=pixel; softmax + mask fold
  float acc[24];
#pragma unroll
  for (int j = 0; j < 24; ++j)
    acc[j] = pr[j * 128 + lane] + pr[j * 128 + 64 + lane];
#pragma unroll
  for (int j = 0; j < 16; ++j) acc[j] += bo[j];
#pragma unroll
  for (int j = 0; j < 8; ++j) acc[16 + j] += bw[j];

  float m = acc[16];
#pragma unroll
  for (int k = 1; k < K_; ++k) m = fmaxf(m, acc[16 + k]);
  float s = 0.f;
#pragma unroll
  for (int k = 0; k < K_; ++k) s += __expf(acc[16 + k] - m);
  const bool act = (mask[p0 + lane] != 0);
  const float inv = (act ? 1.f : 0.f) / s;

  const int hw = hw0 + lane;
  const int y = hw / W_;
  const int x = hw - y * W_;

  // wave wv writes k = 2wv, 2wv+1 (6 coalesced 256B stores)
#pragma unroll
  for (int t = 0; t < 2; ++t) {
    const int k = wv * 2 + t;
    trip[(size_t)(k * 3 + 0) * NP_ + p0 + lane] = (float)x + acc[2 * k];
    trip[(size_t)(k * 3 + 1) * NP_ + p0 + lane] = (float)y + acc[2 * k + 1];
    trip[(size_t)(k * 3 + 2) * NP_ + p0 + lane] = __expf(acc[16 + k] - m) * inv;
  }
}

// ====== K2: record expansion + compacted fp16 gather + epilogue ======
// LDS (uints, 7808 = 31232 B): tlds f32[24][64] @ [0,1536);
// reco uint4[8][64] @ [1536,3584); recw uint4[8][64] @ [3584,5632);
// resb uint[64][33] @ [5632,7744); actl @ [7744,7808)
__global__ __launch_bounds__(256) void gatherh_kernel(
    const float* __restrict__ feat, const int* __restrict__ mask,
    const unsigned short* __restrict__ ws, const float* __restrict__ trip,
    float* __restrict__ out) {
  __shared__ uint smem[7808];
  float* tlds = (float*)smem;
  uint4* reco = (uint4*)(smem + 1536);
  uint4* recw = (uint4*)(smem + 3584);
  uint* resb = smem + 5632;
  int* actl = (int*)(smem + 7744);

  const int tid = threadIdx.x;
  const int lane = tid & 63;
  const int wv = tid >> 6;
  const int bid = blockIdx.x;
  const int sb = (bid & 7) * (NBLK_ / 8) + (bid >> 3);   // bijective XCD swizzle
  const int p0 = sb * 64;
  const int b = p0 / HW_;
  const int hw0 = p0 - b * HW_;
  const size_t bCHW = (size_t)b * CHW_;
  const int bHW = b * HW_;

  // load triples global -> LDS (coalesced: 4 x 256B segments per instr)
#pragma unroll
  for (int j = 0; j < 6; ++j) {
    const int idx = j * 256 + tid;       // 0..1535
    const int plane = idx >> 6;
    const int wi = idx & 63;
    tlds[idx] = trip[(size_t)plane * NP_ + p0 + wi];
  }

  // ballot + compaction (identical in all 4 waves; lane = pixel)
  const bool act = (mask[p0 + lane] != 0);
  const unsigned long long mball = __ballot(act);
  const int A = __popcll(mball);
  const int aidx = __builtin_amdgcn_mbcnt_hi(
      (unsigned)(mball >> 32), __builtin_amdgcn_mbcnt_lo((unsigned)mball, 0));
  if (act) actl[aidx] = lane;
  if (A > 0) {
    const int first = __ffsll((unsigned long long)mball) - 1;
    if (lane >= A) actl[lane] = first;   // sentinel pad (loads only)
  }
  __syncthreads();   // b1: tlds + actl ready

  // record expansion: ALL lanes. lane = (pxl16, kq4); 2 k's each
  {
    const int pxl = wv * 16 + (lane & 15);
    const int kq = lane >> 4;
    const bool pact = ((mball >> pxl) & 1ull) != 0;
    const int hwp = hw0 + pxl;
    const int yp = hwp / W_;
    (void)yp;
#pragma unroll
    for (int t = 0; t < 2; ++t) {
      const int k = kq * 2 + t;
      const float px = tlds[(k * 3 + 0) * 64 + pxl];
      const float py = tlds[(k * 3 + 1) * 64 + pxl];
      const float wtk = tlds[(k * 3 + 2) * 64 + pxl];
      const float x0f = floorf(px), y0f = floorf(py);
      const float wx = px - x0f, wy = py - y0f;
      const int x0 = (int)x0f, y0 = (int)y0f;
      const int x1 = x0 + 1, y1 = y0 + 1;
      const bool vx0 = ((unsigned)x0 < (unsigned)W_);
      const bool vx1 = ((unsigned)x1 < (unsigned)W_);
      const bool vy0 = ((unsigned)y0 < (unsigned)H_);
      const bool vy1 = ((unsigned)y1 < (unsigned)H_);
      const int cx0 = min(max(x0, 0), W_ - 1), cx1 = min(max(x1, 0), W_ - 1);
      const int cy0 = min(max(y0, 0), H_ - 1), cy1 = min(max(y1, 0), H_ - 1);
      const float w00 = wtk * (1.f - wx) * (1.f - wy) * ((vx0 && vy0) ? 1.f : 0.f);
      const float w01 = wtk * wx * (1.f - wy) * ((vx1 && vy0) ? 1.f : 0.f);
      const float w10 = wtk * (1.f - wx) * wy * ((vx0 && vy1) ? 1.f : 0.f);
      const float w11 = wtk * wx * wy * ((vx1 && vy1) ? 1.f : 0.f);
      uint4 o;
      o.x = pact ? (uint)((bHW + cy0 * W_ + cx0) << 7) : 0u;
      o.y = pact ? (uint)((bHW + cy0 * W_ + cx1) << 7) : 0u;
      o.z = pact ? (uint)((bHW + cy1 * W_ + cx0) << 7) : 0u;
      o.w = pact ? (uint)((bHW + cy1 * W_ + cx1) << 7) : 0u;
      uint4 wq;
      wq.x = h2u(__float2half2_rn(w00));   // (w,w) duplicated for pk_fma
      wq.y = h2u(__float2half2_rn(w01));
      wq.z = h2u(__float2half2_rn(w10));
      wq.w = h2u(__float2half2_rn(w11));
      reco[k * 64 + pxl] = o;
      recw[k * 64 + pxl] = wq;
    }
  }
  // zero res rows (masked pixels keep zeros)
#pragma unroll
  for (int j = 0; j < 9; ++j) {
    const int idx = j * 256 + tid;
    if (idx < 2112) resb[idx] = 0u;
  }
  __syncthreads();   // b2: records + zeros ready

  // compacted gather. lane = (pg8, cg8 of 8 fp16 ch)
  const int pg = lane >> 3;
  const int cg = lane & 7;
  const int cgb = cg * 16;             // byte offset within 128B row
  const char* ftb = (const char*)ws;
  const int tot = (A + 7) >> 3;

#define ACCH(V, WU)                                                        \
  do {                                                                     \
    const __half2 wh_ = u2h(WU);                                           \
    rr0 = __hfma2(wh_, u2h((V).x), rr0);                                   \
    rr1 = __hfma2(wh_, u2h((V).y), rr1);                                   \
    rr2 = __hfma2(wh_, u2h((V).z), rr2);                                   \
    rr3 = __hfma2(wh_, u2h((V).w), rr3);                                   \
  } while (0)

  for (int i = wv; i < tot; i += 4) {   // round-robin passes across waves
    const int gi = i * 8 + pg;
    const int pxl = actl[gi];           // sentinel-padded
    __half2 rr0 = __float2half2_rn(0.f), rr1 = rr0, rr2 = rr0, rr3 = rr0;
#pragma unroll
    for (int k2 = 0; k2 < 4; ++k2) {    // k pair: 8 staged loads in flight
      const int k0 = 2 * k2, k1 = 2 * k2 + 1;
      const uint4 o0 = reco[k0 * 64 + pxl];
      const uint4 w0 = recw[k0 * 64 + pxl];
      const uint4 o1 = reco[k1 * 64 + pxl];
      const uint4 w1 = recw[k1 * 64 + pxl];
      const uint4 v0 = *(const uint4*)(ftb + (o0.x + cgb));
      const uint4 v1 = *(const uint4*)(ftb + (o0.y + cgb));
      const uint4 v2 = *(const uint4*)(ftb + (o0.z + cgb));
      const uint4 v3 = *(const uint4*)(ftb + (o0.w + cgb));
      const uint4 v4 = *(const uint4*)(ftb + (o1.x + cgb));
      const uint4 v5 = *(const uint4*)(ftb + (o1.y + cgb));
      const uint4 v6 = *(const uint4*)(ftb + (o1.z + cgb));
      const uint4 v7 = *(const uint4*)(ftb + (o1.w + cgb));
      ACCH(v0, w0.x); ACCH(v1, w0.y); ACCH(v2, w0.z); ACCH(v3, w0.w);
      ACCH(v4, w1.x); ACCH(v5, w1.y); ACCH(v6, w1.z); ACCH(v7, w1.w);
    }
    if (gi < A) {                       // sentinel passes don't write
      const int base = pxl * 33 + cg * 4;
      resb[base + 0] = h2u(rr0);
      resb[base + 1] = h2u(rr1);
      resb[base + 2] = h2u(rr2);
      resb[base + 3] = h2u(rr3);
    }
  }
#undef ACCH
  __syncthreads();   // b3: res ready

  // epilogue: out = feat + res, coalesced NCHW
#pragma unroll
  for (int cc = 0; cc < 8; ++cc) {
    const int cp = wv * 8 + cc;               // channel pair {2cp, 2cp+1}
    const float2 f = __half22float2(u2h(resb[lane * 33 + cp]));
    const size_t off = bCHW + (size_t)(2 * cp) * HW_ + hw0 + lane;
    out[off] = feat[off] + f.x;
    out[off + HW_] = feat[off + HW_] + f.y;
  }
}

// =================== Fallback (ws-free, round-1 fused) ===================
__global__ __launch_bounds__(256) void fused_kernel(
    const float* __restrict__ feat, const int* __restrict__ mask,
    const float* __restrict__ Wo, const float* __restrict__ bo,
    const float* __restrict__ Ww, const float* __restrict__ bw,
    float* __restrict__ out) {
  const int p = blockIdx.x * blockDim.x + threadIdx.x;
  const int b = p / HW_;
  const int hw = p - b * HW_;
  const int y = hw / W_;
  const int x = hw - y * W_;
  const float* fb = feat + b * CHW_;
  float acc[24];
#pragma unroll
  for (int i = 0; i < 16; ++i) acc[i] = bo[i];
#pragma unroll
  for (int i = 0; i < 8; ++i) acc[16 + i] = bw[i];
#pragma unroll
  for (int c = 0; c < C_; ++c) {
    const float v = fb[c * HW_ + hw];
#pragma unroll
    for (int i = 0; i < 16; ++i) acc[i] = fmaf(Wo[i * C_ + c], v, acc[i]);
#pragma unroll
    for (int i = 0; i < 8; ++i) acc[16 + i] = fmaf(Ww[i * C_ + c], v, acc[16 + i]);
  }
  float m = acc[16];
#pragma unroll
  for (int k = 1; k < K_; ++k) m = fmaxf(m, acc[16 + k]);
  float wt[K_];
  float s = 0.f;
#pragma unroll
  for (int k = 0; k < K_; ++k) { wt[k] = __expf(acc[16 + k] - m); s += wt[k]; }
  const float fm = (mask[p] != 0) ? 1.f : 0.f;
  const float inv = fm / s;
#pragma unroll
  for (int k = 0; k < K_; ++k) wt[k] *= inv;
  float res[C_];
#pragma unroll
  for (int c = 0; c < C_; ++c) res[c] = 0.f;
  if (fm != 0.f) {
#pragma unroll
    for (int k = 0; k < K_; ++k) {
      const float px = (float)x + acc[2 * k];
      const float py = (float)y + acc[2 * k + 1];
      const float x0f = floorf(px), y0f = floorf(py);
      const float wx = px - x0f, wy = py - y0f;
      const int x0 = (int)x0f, y0 = (int)y0f;
      const int x1 = x0 + 1, y1 = y0 + 1;
      const bool vx0 = ((unsigned)x0 < (unsigned)W_);
      const bool vx1 = ((unsigned)x1 < (unsigned)W_);
      const bool vy0 = ((unsigned)y0 < (unsigned)H_);
      const bool vy1 = ((unsigned)y1 < (unsigned)H_);
      const int cx0 = min(max(x0, 0), W_ - 1), cx1 = min(max(x1, 0), W_ - 1);
      const int cy0 = min(max(y0, 0), H_ - 1), cy1 = min(max(y1, 0), H_ - 1);
      const float wk = wt[k];
      const float w00 = wk * (1.f - wx) * (1.f - wy) * ((vx0 && vy0) ? 1.f : 0.f);
      const float w01 = wk * wx * (1.f - wy) * ((vx1 && vy0) ? 1.f : 0.f);
      const float w10 = wk * (1.f - wx) * wy * ((vx0 && vy1) ? 1.f : 0.f);
      const float w11 = wk * wx * wy * ((vx1 && vy1) ? 1.f : 0.f);
      const int i00 = cy0 * W_ + cx0, i01 = cy0 * W_ + cx1;
      const int i10 = cy1 * W_ + cx0, i11 = cy1 * W_ + cx1;
#pragma unroll
      for (int c = 0; c < C_; ++c) {
        const float* fc = fb + c * HW_;
        res[c] += w00 * fc[i00] + w01 * fc[i01] + w10 * fc[i10] + w11 * fc[i11];
      }
    }
  }
#pragma unroll
  for (int c = 0; c < C_; ++c)
    out[b * CHW_ + c * HW_ + hw] = fb[c * HW_ + hw] + res[c];
}

extern "C" void kernel_launch(void* const* d_in, const int* in_sizes, int n_in,
                              void* d_out, int out_size, void* d_ws, size_t ws_size,
                              hipStream_t stream) {
  const float* feat = (const float*)d_in[0];
  const int* mask = (const int*)d_in[1];
  const float* Wo = (const float*)d_in[2];
  const float* bo = (const float*)d_in[3];
  const float* Ww = (const float*)d_in[4];
  const float* bw = (const float*)d_in[5];
  float* out = (float*)d_out;

  if (ws_size >= WS_NEED_) {
    unsigned short* ft = (unsigned short*)d_ws;
    float* trip = (float*)((char*)d_ws + FT_BYTES_);
    hipLaunchKernelGGL(prep_kernel, dim3(NBLK_), dim3(256), 0, stream,
                       feat, mask, Wo, bo, Ww, bw, ft, trip);
    hipLaunchKernelGGL(gatherh_kernel, dim3(NBLK_), dim3(256), 0, stream,
                       feat, mask, ft, trip, out);
  } else {
    hipLaunchKernelGGL(fused_kernel, dim3(NP_ / 256), dim3(256), 0, stream,
                       feat, mask, Wo, bo, Ww, bw, out);
  }
}

// Round 11
// 45.118 us; speedup vs baseline: 1.2908x; 1.2908x over previous
//
#include <hip/hip_runtime.h>
#include <hip/hip_fp16.h>

#define B_ 2
#define C_ 64
#define H_ 192
#define W_ 384
#define K_ 8
constexpr int HW_ = H_ * W_;
constexpr int CHW_ = C_ * HW_;
constexpr int NP_ = B_ * HW_;           // 147456
constexpr int NBLK_ = NP_ / 64;         // 2304, %8==0
// ws: ft fp16 NHWC [NP][64] then trip fp32 [24][NP]
constexpr size_t FT_BYTES_ = (size_t)NP_ * 64 * sizeof(unsigned short);   // 18.9 MB
constexpr size_t WS_NEED_ = FT_BYTES_ + (size_t)24 * NP_ * sizeof(float); // 33.0 MB

typedef _Float16 h8 __attribute__((ext_vector_type(8)));
typedef float f32x4 __attribute__((ext_vector_type(4)));

static __device__ __forceinline__ __half2 u2h(uint u) {
  union { uint u; __half2 h; } x; x.u = u; return x.h;
}
static __device__ __forceinline__ uint h2u(__half2 h) {
  union { uint u; __half2 h; } x; x.h = h; return x.u;
}

// ====== K1: fp16 NHWC transpose + MFMA conv + softmax + triple write ======
// block = 256 thr = 4 waves, 64 pixels.
// LDS (uints, 3840 = 15360 B): stagh fp16[64 px][72] @ [0,2304);
//                              clds f32[24][64] @ [2304,3840)
__global__ __launch_bounds__(256) void prep_kernel(
    const float* __restrict__ feat, const int* __restrict__ mask,
    const float* __restrict__ Wo, const float* __restrict__ bo,
    const float* __restrict__ Ww, const float* __restrict__ bw,
    unsigned short* __restrict__ ft, float* __restrict__ trip) {
  __shared__ uint smem[3840];
  const unsigned short* sth = (const unsigned short*)smem;
  float* clds = (float*)(smem + 2304);

  const int tid = threadIdx.x;
  const int lane = tid & 63;
  const int wv = tid >> 6;
  const int p0 = blockIdx.x * 64;
  const int b = p0 / HW_;
  const int hw0 = p0 - b * HW_;
  const float* fb = feat + (size_t)b * CHW_;

  // ---- phase A: load 16 channels of pixel `lane`, pack fp16 pairs into LDS ----
#pragma unroll
  for (int cc = 0; cc < 16; cc += 2) {
    const int c = wv * 16 + cc;
    const float v0 = fb[(size_t)c * HW_ + hw0 + lane];        // coalesced 256B
    const float v1 = fb[(size_t)(c + 1) * HW_ + hw0 + lane];
    smem[lane * 36 + (c >> 1)] = h2u(__floats2half2_rn(v0, v1));
  }
  __syncthreads();   // b1: stagh complete

  // ---- A-fragments from global weights (each wave identical; L1-cached) ----
  const int mrow = lane & 15;
  const int kq = lane >> 4;            // 0..3
  h8 afr[2][2];
#pragma unroll
  for (int mt = 0; mt < 2; ++mt) {
    const int row = mt * 16 + mrow;    // out-channel 0..31 (24..31 padded)
    const float* wrow = (row < 16) ? (Wo + row * 64)
                                   : (Ww + (((row - 16) < 8 ? (row - 16) : 7) * 64));
    const float z = (row < 24) ? 1.f : 0.f;
#pragma unroll
    for (int k0 = 0; k0 < 2; ++k0) {
      const float4 a = *(const float4*)(wrow + k0 * 32 + kq * 8);
      const float4 bq = *(const float4*)(wrow + k0 * 32 + kq * 8 + 4);
      h8 h;
      h[0] = (_Float16)(a.x * z);  h[1] = (_Float16)(a.y * z);
      h[2] = (_Float16)(a.z * z);  h[3] = (_Float16)(a.w * z);
      h[4] = (_Float16)(bq.x * z); h[5] = (_Float16)(bq.y * z);
      h[6] = (_Float16)(bq.z * z); h[7] = (_Float16)(bq.w * z);
      afr[mt][k0] = h;
    }
  }

  // ---- ft write (reads stagh; stores drain during MFMA) ----
  uint* ft32 = (uint*)ft;
#pragma unroll
  for (int j = 0; j < 8; ++j) {
    const int idx = j * 256 + tid;
    const int row = idx >> 5;            // pixel 0..63
    const int cp = idx & 31;             // channel pair
    ft32[(size_t)(p0 + row) * 32 + cp] = smem[row * 36 + cp];
  }

  // ---- MFMA: wave wv -> pixels wv*16..wv*16+15; [32 out][16 px] ----
  const int px = wv * 16 + mrow;       // B's n index -> pixel
  f32x4 ac0 = {0.f, 0.f, 0.f, 0.f};
  f32x4 ac1 = {0.f, 0.f, 0.f, 0.f};
#pragma unroll
  for (int k0 = 0; k0 < 2; ++k0) {
    const h8 bf = *(const h8*)(sth + px * 72 + k0 * 32 + kq * 8);  // ds_read_b128
    ac0 = __builtin_amdgcn_mfma_f32_16x16x32_f16(afr[0][k0], bf, ac0, 0, 0, 0);
    ac1 = __builtin_amdgcn_mfma_f32_16x16x32_f16(afr[1][k0], bf, ac1, 0, 0, 0);
  }
  // D[m][n]: n = lane&15 (=px), m = kq*4 + r
#pragma unroll
  for (int r = 0; r < 4; ++r) clds[(kq * 4 + r) * 64 + px] = ac0[r];
  if (kq < 2) {
#pragma unroll
    for (int r = 0; r < 4; ++r) clds[(16 + kq * 4 + r) * 64 + px] = ac1[r];
  }
  __syncthreads();   // b2: clds complete

  // ---- softmax per lane=pixel + trip write (wave wv owns k=2wv,2wv+1) ----
  float acc[24];
#pragma unroll
  for (int j = 0; j < 24; ++j) acc[j] = clds[j * 64 + lane];
#pragma unroll
  for (int j = 0; j < 16; ++j) acc[j] += bo[j];
#pragma unroll
  for (int j = 0; j < 8; ++j) acc[16 + j] += bw[j];

  float m = acc[16];
#pragma unroll
  for (int k = 1; k < K_; ++k) m = fmaxf(m, acc[16 + k]);
  float s = 0.f;
#pragma unroll
  for (int k = 0; k < K_; ++k) s += __expf(acc[16 + k] - m);
  const bool act = (mask[p0 + lane] != 0);
  const float inv = (act ? 1.f : 0.f) / s;

  const int hw = hw0 + lane;
  const int y = hw / W_;
  const int x = hw - y * W_;

#pragma unroll
  for (int t = 0; t < 2; ++t) {
    const int k = wv * 2 + t;
    trip[(size_t)(k * 3 + 0) * NP_ + p0 + lane] = (float)x + acc[2 * k];
    trip[(size_t)(k * 3 + 1) * NP_ + p0 + lane] = (float)y + acc[2 * k + 1];
    trip[(size_t)(k * 3 + 2) * NP_ + p0 + lane] = __expf(acc[16 + k] - m) * inv;
  }
}

// ====== K2: record expansion + compacted fp16 gather + epilogue ======
// LDS (uints, 7808 = 31232 B): tlds f32[24][64] @ [0,1536);
// reco uint4[8][64] @ [1536,3584); recw uint4[8][64] @ [3584,5632);
// resb uint[64][33] @ [5632,7744); actl @ [7744,7808)
__global__ __launch_bounds__(256) void gatherh_kernel(
    const float* __restrict__ feat, const int* __restrict__ mask,
    const unsigned short* __restrict__ ws, const float* __restrict__ trip,
    float* __restrict__ out) {
  __shared__ uint smem[7808];
  float* tlds = (float*)smem;
  uint4* reco = (uint4*)(smem + 1536);
  uint4* recw = (uint4*)(smem + 3584);
  uint* resb = smem + 5632;
  int* actl = (int*)(smem + 7744);

  const int tid = threadIdx.x;
  const int lane = tid & 63;
  const int wv = tid >> 6;
  const int bid = blockIdx.x;
  const int sb = (bid & 7) * (NBLK_ / 8) + (bid >> 3);   // bijective XCD swizzle
  const int p0 = sb * 64;
  const int b = p0 / HW_;
  const int hw0 = p0 - b * HW_;
  const size_t bCHW = (size_t)b * CHW_;
  const int bHW = b * HW_;

  // load triples global -> LDS (coalesced)
#pragma unroll
  for (int j = 0; j < 6; ++j) {
    const int idx = j * 256 + tid;       // 0..1535
    const int plane = idx >> 6;
    const int wi = idx & 63;
    tlds[idx] = trip[(size_t)plane * NP_ + p0 + wi];
  }

  // ballot + compaction (identical in all 4 waves; lane = pixel)
  const bool act = (mask[p0 + lane] != 0);
  const unsigned long long mball = __ballot(act);
  const int A = __popcll(mball);
  const int aidx = __builtin_amdgcn_mbcnt_hi(
      (unsigned)(mball >> 32), __builtin_amdgcn_mbcnt_lo((unsigned)mball, 0));
  if (act) actl[aidx] = lane;
  if (A > 0) {
    const int first = __ffsll((unsigned long long)mball) - 1;
    if (lane >= A) actl[lane] = first;   // sentinel pad (loads only)
  }
  __syncthreads();   // b1: tlds + actl ready

  // record expansion: ALL lanes. lane = (pxl16, kq4); 2 k's each
  {
    const int pxl = wv * 16 + (lane & 15);
    const int kq = lane >> 4;
    const bool pact = ((mball >> pxl) & 1ull) != 0;
#pragma unroll
    for (int t = 0; t < 2; ++t) {
      const int k = kq * 2 + t;
      const float px = tlds[(k * 3 + 0) * 64 + pxl];
      const float py = tlds[(k * 3 + 1) * 64 + pxl];
      const float wtk = tlds[(k * 3 + 2) * 64 + pxl];
      const float x0f = floorf(px), y0f = floorf(py);
      const float wx = px - x0f, wy = py - y0f;
      const int x0 = (int)x0f, y0 = (int)y0f;
      const int x1 = x0 + 1, y1 = y0 + 1;
      const bool vx0 = ((unsigned)x0 < (unsigned)W_);
      const bool vx1 = ((unsigned)x1 < (unsigned)W_);
      const bool vy0 = ((unsigned)y0 < (unsigned)H_);
      const bool vy1 = ((unsigned)y1 < (unsigned)H_);
      const int cx0 = min(max(x0, 0), W_ - 1), cx1 = min(max(x1, 0), W_ - 1);
      const int cy0 = min(max(y0, 0), H_ - 1), cy1 = min(max(y1, 0), H_ - 1);
      const float w00 = wtk * (1.f - wx) * (1.f - wy) * ((vx0 && vy0) ? 1.f : 0.f);
      const float w01 = wtk * wx * (1.f - wy) * ((vx1 && vy0) ? 1.f : 0.f);
      const float w10 = wtk * (1.f - wx) * wy * ((vx0 && vy1) ? 1.f : 0.f);
      const float w11 = wtk * wx * wy * ((vx1 && vy1) ? 1.f : 0.f);
      uint4 o;
      o.x = pact ? (uint)((bHW + cy0 * W_ + cx0) << 7) : 0u;
      o.y = pact ? (uint)((bHW + cy0 * W_ + cx1) << 7) : 0u;
      o.z = pact ? (uint)((bHW + cy1 * W_ + cx0) << 7) : 0u;
      o.w = pact ? (uint)((bHW + cy1 * W_ + cx1) << 7) : 0u;
      uint4 wq;
      wq.x = h2u(__float2half2_rn(w00));   // (w,w) duplicated for pk_fma
      wq.y = h2u(__float2half2_rn(w01));
      wq.z = h2u(__float2half2_rn(w10));
      wq.w = h2u(__float2half2_rn(w11));
      reco[k * 64 + pxl] = o;
      recw[k * 64 + pxl] = wq;
    }
  }
  // zero res rows (masked pixels keep zeros)
#pragma unroll
  for (int j = 0; j < 9; ++j) {
    const int idx = j * 256 + tid;
    if (idx < 2112) resb[idx] = 0u;
  }
  __syncthreads();   // b2: records + zeros ready

  // compacted gather. lane = (pg8, cg8 of 8 fp16 ch)
  const int pg = lane >> 3;
  const int cg = lane & 7;
  const int cgb = cg * 16;             // byte offset within 128B row
  const char* ftb = (const char*)ws;
  const int tot = (A + 7) >> 3;

#define ACCH(V, WU)                                                        \
  do {                                                                     \
    const __half2 wh_ = u2h(WU);                                           \
    rr0 = __hfma2(wh_, u2h((V).x), rr0);                                   \
    rr1 = __hfma2(wh_, u2h((V).y), rr1);                                   \
    rr2 = __hfma2(wh_, u2h((V).z), rr2);                                   \
    rr3 = __hfma2(wh_, u2h((V).w), rr3);                                   \
  } while (0)

  for (int i = wv; i < tot; i += 4) {   // round-robin passes across waves
    const int gi = i * 8 + pg;
    const int pxl = actl[gi];           // sentinel-padded
    __half2 rr0 = __float2half2_rn(0.f), rr1 = rr0, rr2 = rr0, rr3 = rr0;
#pragma unroll
    for (int k2 = 0; k2 < 4; ++k2) {    // k pair: 8 staged loads in flight
      const int k0 = 2 * k2, k1 = 2 * k2 + 1;
      const uint4 o0 = reco[k0 * 64 + pxl];
      const uint4 w0 = recw[k0 * 64 + pxl];
      const uint4 o1 = reco[k1 * 64 + pxl];
      const uint4 w1 = recw[k1 * 64 + pxl];
      const uint4 v0 = *(const uint4*)(ftb + (o0.x + cgb));
      const uint4 v1 = *(const uint4*)(ftb + (o0.y + cgb));
      const uint4 v2 = *(const uint4*)(ftb + (o0.z + cgb));
      const uint4 v3 = *(const uint4*)(ftb + (o0.w + cgb));
      const uint4 v4 = *(const uint4*)(ftb + (o1.x + cgb));
      const uint4 v5 = *(const uint4*)(ftb + (o1.y + cgb));
      const uint4 v6 = *(const uint4*)(ftb + (o1.z + cgb));
      const uint4 v7 = *(const uint4*)(ftb + (o1.w + cgb));
      ACCH(v0, w0.x); ACCH(v1, w0.y); ACCH(v2, w0.z); ACCH(v3, w0.w);
      ACCH(v4, w1.x); ACCH(v5, w1.y); ACCH(v6, w1.z); ACCH(v7, w1.w);
    }
    if (gi < A) {                       // sentinel passes don't write
      const int base = pxl * 33 + cg * 4;
      resb[base + 0] = h2u(rr0);
      resb[base + 1] = h2u(rr1);
      resb[base + 2] = h2u(rr2);
      resb[base + 3] = h2u(rr3);
    }
  }
#undef ACCH
  __syncthreads();   // b3: res ready

  // epilogue: out = feat + res, coalesced NCHW
#pragma unroll
  for (int cc = 0; cc < 8; ++cc) {
    const int cp = wv * 8 + cc;               // channel pair {2cp, 2cp+1}
    const float2 f = __half22float2(u2h(resb[lane * 33 + cp]));
    const size_t off = bCHW + (size_t)(2 * cp) * HW_ + hw0 + lane;
    out[off] = feat[off] + f.x;
    out[off + HW_] = feat[off + HW_] + f.y;
  }
}

// =================== Fallback (ws-free, round-1 fused) ===================
__global__ __launch_bounds__(256) void fused_kernel(
    const float* __restrict__ feat, const int* __restrict__ mask,
    const float* __restrict__ Wo, const float* __restrict__ bo,
    const float* __restrict__ Ww, const float* __restrict__ bw,
    float* __restrict__ out) {
  const int p = blockIdx.x * blockDim.x + threadIdx.x;
  const int b = p / HW_;
  const int hw = p - b * HW_;
  const int y = hw / W_;
  const int x = hw - y * W_;
  const float* fb = feat + b * CHW_;
  float acc[24];
#pragma unroll
  for (int i = 0; i < 16; ++i) acc[i] = bo[i];
#pragma unroll
  for (int i = 0; i < 8; ++i) acc[16 + i] = bw[i];
#pragma unroll
  for (int c = 0; c < C_; ++c) {
    const float v = fb[c * HW_ + hw];
#pragma unroll
    for (int i = 0; i < 16; ++i) acc[i] = fmaf(Wo[i * C_ + c], v, acc[i]);
#pragma unroll
    for (int i = 0; i < 8; ++i) acc[16 + i] = fmaf(Ww[i * C_ + c], v, acc[16 + i]);
  }
  float m = acc[16];
#pragma unroll
  for (int k = 1; k < K_; ++k) m = fmaxf(m, acc[16 + k]);
  float wt[K_];
  float s = 0.f;
#pragma unroll
  for (int k = 0; k < K_; ++k) { wt[k] = __expf(acc[16 + k] - m); s += wt[k]; }
  const float fm = (mask[p] != 0) ? 1.f : 0.f;
  const float inv = fm / s;
#pragma unroll
  for (int k = 0; k < K_; ++k) wt[k] *= inv;
  float res[C_];
#pragma unroll
  for (int c = 0; c < C_; ++c) res[c] = 0.f;
  if (fm != 0.f) {
#pragma unroll
    for (int k = 0; k < K_; ++k) {
      const float px = (float)x + acc[2 * k];
      const float py = (float)y + acc[2 * k + 1];
      const float x0f = floorf(px), y0f = floorf(py);
      const float wx = px - x0f, wy = py - y0f;
      const int x0 = (int)x0f, y0 = (int)y0f;
      const int x1 = x0 + 1, y1 = y0 + 1;
      const bool vx0 = ((unsigned)x0 < (unsigned)W_);
      const bool vx1 = ((unsigned)x1 < (unsigned)W_);
      const bool vy0 = ((unsigned)y0 < (unsigned)H_);
      const bool vy1 = ((unsigned)y1 < (unsigned)H_);
      const int cx0 = min(max(x0, 0), W_ - 1), cx1 = min(max(x1, 0), W_ - 1);
      const int cy0 = min(max(y0, 0), H_ - 1), cy1 = min(max(y1, 0), H_ - 1);
      const float wk = wt[k];
      const float w00 = wk * (1.f - wx) * (1.f - wy) * ((vx0 && vy0) ? 1.f : 0.f);
      const float w01 = wk * wx * (1.f - wy) * ((vx1 && vy0) ? 1.f : 0.f);
      const float w10 = wk * (1.f - wx) * wy * ((vx0 && vy1) ? 1.f : 0.f);
      const float w11 = wk * wx * wy * ((vx1 && vy1) ? 1.f : 0.f);
      const int i00 = cy0 * W_ + cx0, i01 = cy0 * W_ + cx1;
      const int i10 = cy1 * W_ + cx0, i11 = cy1 * W_ + cx1;
#pragma unroll
      for (int c = 0; c < C_; ++c) {
        const float* fc = fb + c * HW_;
        res[c] += w00 * fc[i00] + w01 * fc[i01] + w10 * fc[i10] + w11 * fc[i11];
      }
    }
  }
#pragma unroll
  for (int c = 0; c < C_; ++c)
    out[b * CHW_ + c * HW_ + hw] = fb[c * HW_ + hw] + res[c];
}

extern "C" void kernel_launch(void* const* d_in, const int* in_sizes, int n_in,
                              void* d_out, int out_size, void* d_ws, size_t ws_size,
                              hipStream_t stream) {
  const float* feat = (const float*)d_in[0];
  const int* mask = (const int*)d_in[1];
  const float* Wo = (const float*)d_in[2];
  const float* bo = (const float*)d_in[3];
  const float* Ww = (const float*)d_in[4];
  const float* bw = (const float*)d_in[5];
  float* out = (float*)d_out;

  if (ws_size >= WS_NEED_) {
    unsigned short* ft = (unsigned short*)d_ws;
    float* trip = (float*)((char*)d_ws + FT_BYTES_);
    hipLaunchKernelGGL(prep_kernel, dim3(NBLK_), dim3(256), 0, stream,
                       feat, mask, Wo, bo, Ww, bw, ft, trip);
    hipLaunchKernelGGL(gatherh_kernel, dim3(NBLK_), dim3(256), 0, stream,
                       feat, mask, ft, trip, out);
  } else {
    hipLaunchKernelGGL(fused_kernel, dim3(NP_ / 256), dim3(256), 0, stream,
                       feat, mask, Wo, bo, Ww, bw, out);
  }
}

// Round 12
// 43.920 us; speedup vs baseline: 1.3260x; 1.0273x over previous
//
#include <hip/hip_runtime.h>
#include <hip/hip_fp16.h>

#define B_ 2
#define C_ 64
#define H_ 192
#define W_ 384
#define K_ 8
constexpr int HW_ = H_ * W_;
constexpr int CHW_ = C_ * HW_;
constexpr int NP_ = B_ * HW_;           // 147456
constexpr int NBLK_ = NP_ / 64;         // 2304, %8==0
// ws: ft fp16 NHWC [NP][64] then trip 16 uint planes [16][NP]
constexpr size_t FT_BYTES_ = (size_t)NP_ * 64 * sizeof(unsigned short);   // 18.9 MB
constexpr size_t WS_NEED_ = FT_BYTES_ + (size_t)16 * NP_ * sizeof(uint);  // 28.3 MB

typedef _Float16 h8 __attribute__((ext_vector_type(8)));
typedef float f32x4 __attribute__((ext_vector_type(4)));

static __device__ __forceinline__ __half2 u2h(uint u) {
  union { uint u; __half2 h; } x; x.u = u; return x.h;
}
static __device__ __forceinline__ uint h2u(__half2 h) {
  union { uint u; __half2 h; } x; x.h = h; return x.u;
}

// ====== K1: fp16 NHWC transpose + MFMA conv + softmax + packed trip write ======
// block = 256 thr = 4 waves, 64 pixels.
// LDS (uints, 3840 = 15360 B): stagh fp16[64 px][72] @ [0,2304);
//                              clds f32[24][64] @ [2304,3840)
__global__ __launch_bounds__(256) void prep_kernel(
    const float* __restrict__ feat, const int* __restrict__ mask,
    const float* __restrict__ Wo, const float* __restrict__ bo,
    const float* __restrict__ Ww, const float* __restrict__ bw,
    unsigned short* __restrict__ ft, uint* __restrict__ trip) {
  __shared__ uint smem[3840];
  const unsigned short* sth = (const unsigned short*)smem;
  float* clds = (float*)(smem + 2304);

  const int tid = threadIdx.x;
  const int lane = tid & 63;
  const int wv = tid >> 6;
  const int p0 = blockIdx.x * 64;
  const int b = p0 / HW_;
  const int hw0 = p0 - b * HW_;
  const float* fb = feat + (size_t)b * CHW_;

  // ---- phase A: load 16 channels of pixel `lane`, pack fp16 pairs into LDS ----
#pragma unroll
  for (int cc = 0; cc < 16; cc += 2) {
    const int c = wv * 16 + cc;
    const float v0 = fb[(size_t)c * HW_ + hw0 + lane];        // coalesced 256B
    const float v1 = fb[(size_t)(c + 1) * HW_ + hw0 + lane];
    smem[lane * 36 + (c >> 1)] = h2u(__floats2half2_rn(v0, v1));
  }
  __syncthreads();   // b1: stagh complete

  // ---- A-fragments from global weights (each wave identical; L1-cached) ----
  const int mrow = lane & 15;
  const int kq = lane >> 4;            // 0..3
  h8 afr[2][2];
#pragma unroll
  for (int mt = 0; mt < 2; ++mt) {
    const int row = mt * 16 + mrow;    // out-channel 0..31 (24..31 padded)
    const float* wrow = (row < 16) ? (Wo + row * 64)
                                   : (Ww + (((row - 16) < 8 ? (row - 16) : 7) * 64));
    const float z = (row < 24) ? 1.f : 0.f;
#pragma unroll
    for (int k0 = 0; k0 < 2; ++k0) {
      const float4 a = *(const float4*)(wrow + k0 * 32 + kq * 8);
      const float4 bq = *(const float4*)(wrow + k0 * 32 + kq * 8 + 4);
      h8 h;
      h[0] = (_Float16)(a.x * z);  h[1] = (_Float16)(a.y * z);
      h[2] = (_Float16)(a.z * z);  h[3] = (_Float16)(a.w * z);
      h[4] = (_Float16)(bq.x * z); h[5] = (_Float16)(bq.y * z);
      h[6] = (_Float16)(bq.z * z); h[7] = (_Float16)(bq.w * z);
      afr[mt][k0] = h;
    }
  }

  // ---- ft write (reads stagh; stores drain during MFMA) ----
  uint* ft32 = (uint*)ft;
#pragma unroll
  for (int j = 0; j < 8; ++j) {
    const int idx = j * 256 + tid;
    const int row = idx >> 5;            // pixel 0..63
    const int cp = idx & 31;             // channel pair
    ft32[(size_t)(p0 + row) * 32 + cp] = smem[row * 36 + cp];
  }

  // ---- MFMA: wave wv -> pixels wv*16..wv*16+15; [32 out][16 px] ----
  const int px = wv * 16 + mrow;       // B's n index -> pixel
  f32x4 ac0 = {0.f, 0.f, 0.f, 0.f};
  f32x4 ac1 = {0.f, 0.f, 0.f, 0.f};
#pragma unroll
  for (int k0 = 0; k0 < 2; ++k0) {
    const h8 bf = *(const h8*)(sth + px * 72 + k0 * 32 + kq * 8);  // ds_read_b128
    ac0 = __builtin_amdgcn_mfma_f32_16x16x32_f16(afr[0][k0], bf, ac0, 0, 0, 0);
    ac1 = __builtin_amdgcn_mfma_f32_16x16x32_f16(afr[1][k0], bf, ac1, 0, 0, 0);
  }
  // D[m][n]: n = lane&15 (=px), m = kq*4 + r
#pragma unroll
  for (int r = 0; r < 4; ++r) clds[(kq * 4 + r) * 64 + px] = ac0[r];
  if (kq < 2) {
#pragma unroll
    for (int r = 0; r < 4; ++r) clds[(16 + kq * 4 + r) * 64 + px] = ac1[r];
  }
  __syncthreads();   // b2: clds complete

  // ---- softmax per lane=pixel + packed trip write (wave wv owns k=2wv,2wv+1) ----
  float acc[24];
#pragma unroll
  for (int j = 0; j < 24; ++j) acc[j] = clds[j * 64 + lane];
#pragma unroll
  for (int j = 0; j < 16; ++j) acc[j] += bo[j];
#pragma unroll
  for (int j = 0; j < 8; ++j) acc[16 + j] += bw[j];

  float m = acc[16];
#pragma unroll
  for (int k = 1; k < K_; ++k) m = fmaxf(m, acc[16 + k]);
  float s = 0.f;
#pragma unroll
  for (int k = 0; k < K_; ++k) s += __expf(acc[16 + k] - m);
  const bool act = (mask[p0 + lane] != 0);
  const float inv = (act ? 1.f : 0.f) / s;

#pragma unroll
  for (int t = 0; t < 2; ++t) {
    const int k = wv * 2 + t;
    const float wtk = __expf(acc[16 + k] - m) * inv;
    // packed: u0 = half2(dx, dy); u1 = half2(wt, 0)
    trip[(size_t)(k * 2 + 0) * NP_ + p0 + lane] =
        h2u(__floats2half2_rn(acc[2 * k], acc[2 * k + 1]));
    trip[(size_t)(k * 2 + 1) * NP_ + p0 + lane] =
        h2u(__floats2half2_rn(wtk, 0.f));
  }
}

// ====== K2: record expansion + compacted fp16 gather + ft-based epilogue ======
// LDS (uints, 7296 = 29184 B): tlds uint[16][64] @ [0,1024);
// reco uint4[8][64] @ [1024,3072); recw uint4[8][64] @ [3072,5120);
// resb uint[64][33] @ [5120,7232); actl @ [7232,7296)
__global__ __launch_bounds__(256) void gatherh_kernel(
    const int* __restrict__ mask, const unsigned short* __restrict__ ws,
    const uint* __restrict__ trip, float* __restrict__ out) {
  __shared__ uint smem[7296];
  uint* tlds = smem;
  uint4* reco = (uint4*)(smem + 1024);
  uint4* recw = (uint4*)(smem + 3072);
  uint* resb = smem + 5120;
  int* actl = (int*)(smem + 7232);

  const int tid = threadIdx.x;
  const int lane = tid & 63;
  const int wv = tid >> 6;
  const int bid = blockIdx.x;
  const int sb = (bid & 7) * (NBLK_ / 8) + (bid >> 3);   // bijective XCD swizzle
  const int p0 = sb * 64;
  const int b = p0 / HW_;
  const int hw0 = p0 - b * HW_;
  const size_t bCHW = (size_t)b * CHW_;
  const int bHW = b * HW_;

  // load packed trips global -> LDS (coalesced 256B segments)
#pragma unroll
  for (int j = 0; j < 4; ++j) {
    const int idx = j * 256 + tid;       // 0..1023
    const int plane = idx >> 6;
    const int wi = idx & 63;
    tlds[idx] = trip[(size_t)plane * NP_ + p0 + wi];
  }

  // ballot + compaction (identical in all 4 waves; lane = pixel)
  const bool act = (mask[p0 + lane] != 0);
  const unsigned long long mball = __ballot(act);
  const int A = __popcll(mball);
  const int aidx = __builtin_amdgcn_mbcnt_hi(
      (unsigned)(mball >> 32), __builtin_amdgcn_mbcnt_lo((unsigned)mball, 0));
  if (act) actl[aidx] = lane;
  if (A > 0) {
    const int first = __ffsll((unsigned long long)mball) - 1;
    if (lane >= A) actl[lane] = first;   // sentinel pad (loads only)
  }
  __syncthreads();   // b1: tlds + actl ready

  // record expansion: ALL lanes. lane = (pxl16, kq4); 2 k's each
  {
    const int pxl = wv * 16 + (lane & 15);
    const int kq = lane >> 4;
    const bool pact = ((mball >> pxl) & 1ull) != 0;
    const int hwp = hw0 + pxl;
    const int yp = hwp / W_;
    const int xp = hwp - yp * W_;
#pragma unroll
    for (int t = 0; t < 2; ++t) {
      const int k = kq * 2 + t;
      const float2 d = __half22float2(u2h(tlds[(k * 2 + 0) * 64 + pxl]));
      const float wtk = __half22float2(u2h(tlds[(k * 2 + 1) * 64 + pxl])).x;
      const float px = (float)xp + d.x;
      const float py = (float)yp + d.y;
      const float x0f = floorf(px), y0f = floorf(py);
      const float wx = px - x0f, wy = py - y0f;
      const int x0 = (int)x0f, y0 = (int)y0f;
      const int x1 = x0 + 1, y1 = y0 + 1;
      const bool vx0 = ((unsigned)x0 < (unsigned)W_);
      const bool vx1 = ((unsigned)x1 < (unsigned)W_);
      const bool vy0 = ((unsigned)y0 < (unsigned)H_);
      const bool vy1 = ((unsigned)y1 < (unsigned)H_);
      const int cx0 = min(max(x0, 0), W_ - 1), cx1 = min(max(x1, 0), W_ - 1);
      const int cy0 = min(max(y0, 0), H_ - 1), cy1 = min(max(y1, 0), H_ - 1);
      const float w00 = wtk * (1.f - wx) * (1.f - wy) * ((vx0 && vy0) ? 1.f : 0.f);
      const float w01 = wtk * wx * (1.f - wy) * ((vx1 && vy0) ? 1.f : 0.f);
      const float w10 = wtk * (1.f - wx) * wy * ((vx0 && vy1) ? 1.f : 0.f);
      const float w11 = wtk * wx * wy * ((vx1 && vy1) ? 1.f : 0.f);
      uint4 o;
      o.x = pact ? (uint)((bHW + cy0 * W_ + cx0) << 7) : 0u;
      o.y = pact ? (uint)((bHW + cy0 * W_ + cx1) << 7) : 0u;
      o.z = pact ? (uint)((bHW + cy1 * W_ + cx0) << 7) : 0u;
      o.w = pact ? (uint)((bHW + cy1 * W_ + cx1) << 7) : 0u;
      uint4 wq;
      wq.x = h2u(__float2half2_rn(w00));   // (w,w) duplicated for pk_fma
      wq.y = h2u(__float2half2_rn(w01));
      wq.z = h2u(__float2half2_rn(w10));
      wq.w = h2u(__float2half2_rn(w11));
      reco[k * 64 + pxl] = o;
      recw[k * 64 + pxl] = wq;
    }
  }
  // zero res rows (masked pixels keep zeros)
#pragma unroll
  for (int j = 0; j < 9; ++j) {
    const int idx = j * 256 + tid;
    if (idx < 2112) resb[idx] = 0u;
  }
  __syncthreads();   // b2: records + zeros ready

  // compacted gather. lane = (pg8, cg8 of 8 fp16 ch)
  const int pg = lane >> 3;
  const int cg = lane & 7;
  const int cgb = cg * 16;             // byte offset within 128B row
  const char* ftb = (const char*)ws;
  const int tot = (A + 7) >> 3;

#define ACCH(V, WU)                                                        \
  do {                                                                     \
    const __half2 wh_ = u2h(WU);                                           \
    rr0 = __hfma2(wh_, u2h((V).x), rr0);                                   \
    rr1 = __hfma2(wh_, u2h((V).y), rr1);                                   \
    rr2 = __hfma2(wh_, u2h((V).z), rr2);                                   \
    rr3 = __hfma2(wh_, u2h((V).w), rr3);                                   \
  } while (0)

  for (int i = wv; i < tot; i += 4) {   // round-robin passes across waves
    const int gi = i * 8 + pg;
    const int pxl = actl[gi];           // sentinel-padded
    __half2 rr0 = __float2half2_rn(0.f), rr1 = rr0, rr2 = rr0, rr3 = rr0;
#pragma unroll
    for (int k2 = 0; k2 < 4; ++k2) {    // k pair: 8 staged loads in flight
      const int k0 = 2 * k2, k1 = 2 * k2 + 1;
      const uint4 o0 = reco[k0 * 64 + pxl];
      const uint4 w0 = recw[k0 * 64 + pxl];
      const uint4 o1 = reco[k1 * 64 + pxl];
      const uint4 w1 = recw[k1 * 64 + pxl];
      const uint4 v0 = *(const uint4*)(ftb + (o0.x + cgb));
      const uint4 v1 = *(const uint4*)(ftb + (o0.y + cgb));
      const uint4 v2 = *(const uint4*)(ftb + (o0.z + cgb));
      const uint4 v3 = *(const uint4*)(ftb + (o0.w + cgb));
      const uint4 v4 = *(const uint4*)(ftb + (o1.x + cgb));
      const uint4 v5 = *(const uint4*)(ftb + (o1.y + cgb));
      const uint4 v6 = *(const uint4*)(ftb + (o1.z + cgb));
      const uint4 v7 = *(const uint4*)(ftb + (o1.w + cgb));
      ACCH(v0, w0.x); ACCH(v1, w0.y); ACCH(v2, w0.z); ACCH(v3, w0.w);
      ACCH(v4, w1.x); ACCH(v5, w1.y); ACCH(v6, w1.z); ACCH(v7, w1.w);
    }
    if (gi < A) {                       // sentinel passes don't write
      const int base = pxl * 33 + cg * 4;
      resb[base + 0] = h2u(rr0);
      resb[base + 1] = h2u(rr1);
      resb[base + 2] = h2u(rr2);
      resb[base + 3] = h2u(rr3);
    }
  }
#undef ACCH
  __syncthreads();   // b3: res ready

  // epilogue: out = float(ft) + res, NCHW coalesced stores.
  // ft row reads are 128B-strided (one row per lane) but L1/L2-resident.
  const uint* ft32 = (const uint*)ws;
  const size_t ftrow = (size_t)(p0 + lane) * 32;
#pragma unroll
  for (int cc = 0; cc < 8; ++cc) {
    const int cp = wv * 8 + cc;               // channel pair {2cp, 2cp+1}
    const float2 fv = __half22float2(u2h(ft32[ftrow + cp]));
    const float2 rv = __half22float2(u2h(resb[lane * 33 + cp]));
    const size_t off = bCHW + (size_t)(2 * cp) * HW_ + hw0 + lane;
    out[off] = fv.x + rv.x;
    out[off + HW_] = fv.y + rv.y;
  }
}

// =================== Fallback (ws-free, round-1 fused) ===================
__global__ __launch_bounds__(256) void fused_kernel(
    const float* __restrict__ feat, const int* __restrict__ mask,
    const float* __restrict__ Wo, const float* __restrict__ bo,
    const float* __restrict__ Ww, const float* __restrict__ bw,
    float* __restrict__ out) {
  const int p = blockIdx.x * blockDim.x + threadIdx.x;
  const int b = p / HW_;
  const int hw = p - b * HW_;
  const int y = hw / W_;
  const int x = hw - y * W_;
  const float* fb = feat + b * CHW_;
  float acc[24];
#pragma unroll
  for (int i = 0; i < 16; ++i) acc[i] = bo[i];
#pragma unroll
  for (int i = 0; i < 8; ++i) acc[16 + i] = bw[i];
#pragma unroll
  for (int c = 0; c < C_; ++c) {
    const float v = fb[c * HW_ + hw];
#pragma unroll
    for (int i = 0; i < 16; ++i) acc[i] = fmaf(Wo[i * C_ + c], v, acc[i]);
#pragma unroll
    for (int i = 0; i < 8; ++i) acc[16 + i] = fmaf(Ww[i * C_ + c], v, acc[16 + i]);
  }
  float m = acc[16];
#pragma unroll
  for (int k = 1; k < K_; ++k) m = fmaxf(m, acc[16 + k]);
  float wt[K_];
  float s = 0.f;
#pragma unroll
  for (int k = 0; k < K_; ++k) { wt[k] = __expf(acc[16 + k] - m); s += wt[k]; }
  const float fm = (mask[p] != 0) ? 1.f : 0.f;
  const float inv = fm / s;
#pragma unroll
  for (int k = 0; k < K_; ++k) wt[k] *= inv;
  float res[C_];
#pragma unroll
  for (int c = 0; c < C_; ++c) res[c] = 0.f;
  if (fm != 0.f) {
#pragma unroll
    for (int k = 0; k < K_; ++k) {
      const float px = (float)x + acc[2 * k];
      const float py = (float)y + acc[2 * k + 1];
      const float x0f = floorf(px), y0f = floorf(py);
      const float wx = px - x0f, wy = py - y0f;
      const int x0 = (int)x0f, y0 = (int)y0f;
      const int x1 = x0 + 1, y1 = y0 + 1;
      const bool vx0 = ((unsigned)x0 < (unsigned)W_);
      const bool vx1 = ((unsigned)x1 < (unsigned)W_);
      const bool vy0 = ((unsigned)y0 < (unsigned)H_);
      const bool vy1 = ((unsigned)y1 < (unsigned)H_);
      const int cx0 = min(max(x0, 0), W_ - 1), cx1 = min(max(x1, 0), W_ - 1);
      const int cy0 = min(max(y0, 0), H_ - 1), cy1 = min(max(y1, 0), H_ - 1);
      const float wk = wt[k];
      const float w00 = wk * (1.f - wx) * (1.f - wy) * ((vx0 && vy0) ? 1.f : 0.f);
      const float w01 = wk * wx * (1.f - wy) * ((vx1 && vy0) ? 1.f : 0.f);
      const float w10 = wk * (1.f - wx) * wy * ((vx0 && vy1) ? 1.f : 0.f);
      const float w11 = wk * wx * wy * ((vx1 && vy1) ? 1.f : 0.f);
      const int i00 = cy0 * W_ + cx0, i01 = cy0 * W_ + cx1;
      const int i10 = cy1 * W_ + cx0, i11 = cy1 * W_ + cx1;
#pragma unroll
      for (int c = 0; c < C_; ++c) {
        const float* fc = fb + c * HW_;
        res[c] += w00 * fc[i00] + w01 * fc[i01] + w10 * fc[i10] + w11 * fc[i11];
      }
    }
  }
#pragma unroll
  for (int c = 0; c < C_; ++c)
    out[b * CHW_ + c * HW_ + hw] = fb[c * HW_ + hw] + res[c];
}

extern "C" void kernel_launch(void* const* d_in, const int* in_sizes, int n_in,
                              void* d_out, int out_size, void* d_ws, size_t ws_size,
                              hipStream_t stream) {
  const float* feat = (const float*)d_in[0];
  const int* mask = (const int*)d_in[1];
  const float* Wo = (const float*)d_in[2];
  const float* bo = (const float*)d_in[3];
  const float* Ww = (const float*)d_in[4];
  const float* bw = (const float*)d_in[5];
  float* out = (float*)d_out;

  if (ws_size >= WS_NEED_) {
    unsigned short* ft = (unsigned short*)d_ws;
    uint* trip = (uint*)((char*)d_ws + FT_BYTES_);
    hipLaunchKernelGGL(prep_kernel, dim3(NBLK_), dim3(256), 0, stream,
                       feat, mask, Wo, bo, Ww, bw, ft, trip);
    hipLaunchKernelGGL(gatherh_kernel, dim3(NBLK_), dim3(256), 0, stream,
                       mask, ft, trip, out);
  } else {
    hipLaunchKernelGGL(fused_kernel, dim3(NP_ / 256), dim3(256), 0, stream,
                       feat, mask, Wo, bo, Ww, bw, out);
  }
}

// Round 13
// 42.170 us; speedup vs baseline: 1.3810x; 1.0415x over previous
//
#include <hip/hip_runtime.h>
#include <hip/hip_fp16.h>

#define B_ 2
#define C_ 64
#define H_ 192
#define W_ 384
#define K_ 8
constexpr int HW_ = H_ * W_;
constexpr int CHW_ = C_ * HW_;
constexpr int NP_ = B_ * HW_;           // 147456
constexpr int NBLK_ = NP_ / 64;         // 2304, %8==0
constexpr size_t WS_NEED_ = (size_t)NP_ * 64 * sizeof(unsigned short);  // 18.9 MB fp16 NHWC

typedef _Float16 h8 __attribute__((ext_vector_type(8)));
typedef float f32x4 __attribute__((ext_vector_type(4)));

static __device__ __forceinline__ __half2 u2h(uint u) {
  union { uint u; __half2 h; } x; x.u = u; return x.h;
}
static __device__ __forceinline__ uint h2u(__half2 h) {
  union { uint u; __half2 h; } x; x.h = h; return x.u;
}

// =================== K1: NCHW fp32 -> NHWC fp16 transpose (swizzled) ===================
__global__ __launch_bounds__(256) void transposeh_kernel(
    const float* __restrict__ feat, unsigned short* __restrict__ ft) {
  __shared__ float lds[64 * 65];
  const int tid = threadIdx.x;
  const int lane = tid & 63;
  const int wv = tid >> 6;
  const int bid = blockIdx.x;
  const int sb = (bid & 7) * (NBLK_ / 8) + (bid >> 3);   // match K2's tile->XCD map
  const int p0 = sb * 64;
  const int b = p0 / HW_;
  const int hw0 = p0 - b * HW_;
  const float* fb = feat + (size_t)b * CHW_;
#pragma unroll
  for (int cc = 0; cc < 16; ++cc) {
    const int c = wv * 16 + cc;
    lds[lane * 65 + c] = fb[(size_t)c * HW_ + hw0 + lane];   // coalesced 256B
  }
  __syncthreads();
  uint* ft32 = (uint*)ft;
#pragma unroll
  for (int j = 0; j < 8; ++j) {
    const int idx = j * 256 + tid;       // uint index within block tile
    const int row = idx >> 5;            // pixel 0..63
    const int cp = idx & 31;             // channel pair
    const __half2 h = __floats2half2_rn(lds[row * 65 + 2 * cp],
                                        lds[row * 65 + 2 * cp + 1]);
    ft32[(size_t)(p0 + row) * 32 + cp] = h2u(h);
  }
}

// ====== K2: MFMA conv (from ft) + softmax + records + compacted gather + epilogue ======
// block = 256 thr = 4 waves, 64 pixels. LDS (uints, 6272 = 25088 B):
//  era1: stagh fp16[64 px][72] @ [0,2304); clds f32[24][64] @ [2304,3840)
//  era2 (after b3): reco uint4[8][64] @ [0,2048); recw uint4[8][64] @ [2048,4096)
//  persistent (disjoint from era1): resb uint[64][33] @ [4096,6208); actl @ [6208,6272)
__global__ __launch_bounds__(256) void mega_kernel(
    const int* __restrict__ mask,
    const float* __restrict__ Wo, const float* __restrict__ bo,
    const float* __restrict__ Ww, const float* __restrict__ bw,
    const unsigned short* __restrict__ ws, float* __restrict__ out) {
  __shared__ uint smem[6272];
  const unsigned short* sth = (const unsigned short*)smem;
  float* clds = (float*)(smem + 2304);
  uint4* reco = (uint4*)smem;
  uint4* recw = (uint4*)(smem + 2048);
  uint* resb = smem + 4096;
  int* actl = (int*)(smem + 6208);

  const int tid = threadIdx.x;
  const int lane = tid & 63;
  const int wv = tid >> 6;
  const int bid = blockIdx.x;
  const int sb = (bid & 7) * (NBLK_ / 8) + (bid >> 3);   // bijective XCD swizzle
  const int p0 = sb * 64;
  const int b = p0 / HW_;
  const int hw0 = p0 - b * HW_;
  const size_t bCHW = (size_t)b * CHW_;
  const int bHW = b * HW_;

  // ---- phase 1: own ft rows -> LDS stagh (fp16, already packed); zero resb; ballot ----
  const uint4* ftq = (const uint4*)ws;
#pragma unroll
  for (int e = 0; e < 2; ++e) {
    const int j = tid * 2 + e;           // 0..511 uint4s = 64 rows x 8 quads
    const int row = j >> 3;
    const int q = j & 7;
    const uint4 v = ftq[(size_t)p0 * 8 + j];             // 32B/thread, coalesced
    *(uint4*)(smem + row * 36 + q * 4) = v;              // pad 4 uints/row
  }
  const bool act = (mask[p0 + lane] != 0);
  const unsigned long long mball = __ballot(act);
  const int A = __popcll(mball);
#pragma unroll
  for (int j = 0; j < 9; ++j) {          // resb zero (disjoint from era1)
    const int idx = j * 256 + tid;
    if (idx < 2112) resb[idx] = 0u;
  }
  __syncthreads();   // b1: stagh ready

  // ---- phase 2: A-fragments + MFMA conv ----
  const int mrow = lane & 15;
  const int kq = lane >> 4;            // 0..3
  h8 afr[2][2];
#pragma unroll
  for (int mt = 0; mt < 2; ++mt) {
    const int row = mt * 16 + mrow;    // out-channel 0..31 (24..31 padded)
    const float* wrow = (row < 16) ? (Wo + row * 64)
                                   : (Ww + (((row - 16) < 8 ? (row - 16) : 7) * 64));
    const float z = (row < 24) ? 1.f : 0.f;
#pragma unroll
    for (int k0 = 0; k0 < 2; ++k0) {
      const float4 a = *(const float4*)(wrow + k0 * 32 + kq * 8);
      const float4 bq = *(const float4*)(wrow + k0 * 32 + kq * 8 + 4);
      h8 h;
      h[0] = (_Float16)(a.x * z);  h[1] = (_Float16)(a.y * z);
      h[2] = (_Float16)(a.z * z);  h[3] = (_Float16)(a.w * z);
      h[4] = (_Float16)(bq.x * z); h[5] = (_Float16)(bq.y * z);
      h[6] = (_Float16)(bq.z * z); h[7] = (_Float16)(bq.w * z);
      afr[mt][k0] = h;
    }
  }
  const int px = wv * 16 + mrow;       // B's n index -> pixel
  f32x4 ac0 = {0.f, 0.f, 0.f, 0.f};
  f32x4 ac1 = {0.f, 0.f, 0.f, 0.f};
#pragma unroll
  for (int k0 = 0; k0 < 2; ++k0) {
    const h8 bf = *(const h8*)(sth + px * 72 + k0 * 32 + kq * 8);  // ds_read_b128
    ac0 = __builtin_amdgcn_mfma_f32_16x16x32_f16(afr[0][k0], bf, ac0, 0, 0, 0);
    ac1 = __builtin_amdgcn_mfma_f32_16x16x32_f16(afr[1][k0], bf, ac1, 0, 0, 0);
  }
  // D[m][n]: n = lane&15 (=px), m = kq*4 + r
#pragma unroll
  for (int r = 0; r < 4; ++r) clds[(kq * 4 + r) * 64 + px] = ac0[r];
  if (kq < 2) {
#pragma unroll
    for (int r = 0; r < 4; ++r) clds[(16 + kq * 4 + r) * 64 + px] = ac1[r];
  }
  __syncthreads();   // b2: clds complete

  // ---- phase 3a: read acc (lane = pixel) ----
  float acc[24];
#pragma unroll
  for (int j = 0; j < 24; ++j) acc[j] = clds[j * 64 + lane];
  __syncthreads();   // b3: era1 dead -> records may overwrite

  // ---- phase 3b: softmax + records directly to LDS (wave wv owns k=2wv,2wv+1) ----
#pragma unroll
  for (int j = 0; j < 16; ++j) acc[j] += bo[j];
#pragma unroll
  for (int j = 0; j < 8; ++j) acc[16 + j] += bw[j];
  float m = acc[16];
#pragma unroll
  for (int k = 1; k < K_; ++k) m = fmaxf(m, acc[16 + k]);
  float s = 0.f;
#pragma unroll
  for (int k = 0; k < K_; ++k) s += __expf(acc[16 + k] - m);
  const float inv = (act ? 1.f : 0.f) / s;

  const int hw = hw0 + lane;
  const int y = hw / W_;
  const int x = hw - y * W_;

#pragma unroll
  for (int t = 0; t < 2; ++t) {
    const int k = wv * 2 + t;
    const float wtk = __expf(acc[16 + k] - m) * inv;
    const float pxf = (float)x + acc[2 * k];
    const float pyf = (float)y + acc[2 * k + 1];
    const float x0f = floorf(pxf), y0f = floorf(pyf);
    const float wx = pxf - x0f, wy = pyf - y0f;
    const int x0 = (int)x0f, y0 = (int)y0f;
    const int x1 = x0 + 1, y1 = y0 + 1;
    const bool vx0 = ((unsigned)x0 < (unsigned)W_);
    const bool vx1 = ((unsigned)x1 < (unsigned)W_);
    const bool vy0 = ((unsigned)y0 < (unsigned)H_);
    const bool vy1 = ((unsigned)y1 < (unsigned)H_);
    const int cx0 = min(max(x0, 0), W_ - 1), cx1 = min(max(x1, 0), W_ - 1);
    const int cy0 = min(max(y0, 0), H_ - 1), cy1 = min(max(y1, 0), H_ - 1);
    const float w00 = wtk * (1.f - wx) * (1.f - wy) * ((vx0 && vy0) ? 1.f : 0.f);
    const float w01 = wtk * wx * (1.f - wy) * ((vx1 && vy0) ? 1.f : 0.f);
    const float w10 = wtk * (1.f - wx) * wy * ((vx0 && vy1) ? 1.f : 0.f);
    const float w11 = wtk * wx * wy * ((vx1 && vy1) ? 1.f : 0.f);
    uint4 o;
    o.x = act ? (uint)((bHW + cy0 * W_ + cx0) << 7) : 0u;
    o.y = act ? (uint)((bHW + cy0 * W_ + cx1) << 7) : 0u;
    o.z = act ? (uint)((bHW + cy1 * W_ + cx0) << 7) : 0u;
    o.w = act ? (uint)((bHW + cy1 * W_ + cx1) << 7) : 0u;
    uint4 wq;
    wq.x = h2u(__float2half2_rn(w00));   // (w,w) duplicated for pk_fma
    wq.y = h2u(__float2half2_rn(w01));
    wq.z = h2u(__float2half2_rn(w10));
    wq.w = h2u(__float2half2_rn(w11));
    reco[k * 64 + lane] = o;
    recw[k * 64 + lane] = wq;
  }
  // compaction list (identical across waves; actl disjoint from era1)
  {
    const int aidx = __builtin_amdgcn_mbcnt_hi(
        (unsigned)(mball >> 32), __builtin_amdgcn_mbcnt_lo((unsigned)mball, 0));
    if (act) actl[aidx] = lane;
    if (A > 0) {
      const int first = __ffsll((unsigned long long)mball) - 1;
      if (lane >= A) actl[lane] = first;   // sentinel pad (loads only)
    }
  }
  __syncthreads();   // b4: records + actl + resb ready

  // ---- phase 4: compacted gather. lane = (pg8, cg8 of 8 fp16 ch) ----
  const int pg = lane >> 3;
  const int cg = lane & 7;
  const int cgb = cg * 16;             // byte offset within 128B row
  const char* ftb = (const char*)ws;
  const int tot = (A + 7) >> 3;

#define ACCH(V, WU)                                                        \
  do {                                                                     \
    const __half2 wh_ = u2h(WU);                                           \
    rr0 = __hfma2(wh_, u2h((V).x), rr0);                                   \
    rr1 = __hfma2(wh_, u2h((V).y), rr1);                                   \
    rr2 = __hfma2(wh_, u2h((V).z), rr2);                                   \
    rr3 = __hfma2(wh_, u2h((V).w), rr3);                                   \
  } while (0)

  for (int i = wv; i < tot; i += 4) {   // round-robin passes across waves
    const int gi = i * 8 + pg;
    const int pxl = actl[gi];           // sentinel-padded
    __half2 rr0 = __float2half2_rn(0.f), rr1 = rr0, rr2 = rr0, rr3 = rr0;
#pragma unroll
    for (int k2 = 0; k2 < 4; ++k2) {    // k pair: 8 staged loads in flight
      const int k0 = 2 * k2, k1 = 2 * k2 + 1;
      const uint4 o0 = reco[k0 * 64 + pxl];
      const uint4 w0 = recw[k0 * 64 + pxl];
      const uint4 o1 = reco[k1 * 64 + pxl];
      const uint4 w1 = recw[k1 * 64 + pxl];
      const uint4 v0 = *(const uint4*)(ftb + (o0.x + cgb));
      const uint4 v1 = *(const uint4*)(ftb + (o0.y + cgb));
      const uint4 v2 = *(const uint4*)(ftb + (o0.z + cgb));
      const uint4 v3 = *(const uint4*)(ftb + (o0.w + cgb));
      const uint4 v4 = *(const uint4*)(ftb + (o1.x + cgb));
      const uint4 v5 = *(const uint4*)(ftb + (o1.y + cgb));
      const uint4 v6 = *(const uint4*)(ftb + (o1.z + cgb));
      const uint4 v7 = *(const uint4*)(ftb + (o1.w + cgb));
      ACCH(v0, w0.x); ACCH(v1, w0.y); ACCH(v2, w0.z); ACCH(v3, w0.w);
      ACCH(v4, w1.x); ACCH(v5, w1.y); ACCH(v6, w1.z); ACCH(v7, w1.w);
    }
    if (gi < A) {                       // sentinel passes don't write
      const int base = pxl * 33 + cg * 4;
      resb[base + 0] = h2u(rr0);
      resb[base + 1] = h2u(rr1);
      resb[base + 2] = h2u(rr2);
      resb[base + 3] = h2u(rr3);
    }
  }
#undef ACCH
  __syncthreads();   // b5: res ready

  // ---- phase 5: epilogue, out = float(ft) + res, NCHW coalesced stores ----
  const uint* ft32 = (const uint*)ws;
  const size_t ftrow = (size_t)(p0 + lane) * 32;
#pragma unroll
  for (int cc = 0; cc < 8; ++cc) {
    const int cp = wv * 8 + cc;               // channel pair {2cp, 2cp+1}
    const float2 fv = __half22float2(u2h(ft32[ftrow + cp]));
    const float2 rv = __half22float2(u2h(resb[lane * 33 + cp]));
    const size_t off = bCHW + (size_t)(2 * cp) * HW_ + hw0 + lane;
    out[off] = fv.x + rv.x;
    out[off + HW_] = fv.y + rv.y;
  }
}

// =================== Fallback (ws-free, round-1 fused) ===================
__global__ __launch_bounds__(256) void fused_kernel(
    const float* __restrict__ feat, const int* __restrict__ mask,
    const float* __restrict__ Wo, const float* __restrict__ bo,
    const float* __restrict__ Ww, const float* __restrict__ bw,
    float* __restrict__ out) {
  const int p = blockIdx.x * blockDim.x + threadIdx.x;
  const int b = p / HW_;
  const int hw = p - b * HW_;
  const int y = hw / W_;
  const int x = hw - y * W_;
  const float* fb = feat + b * CHW_;
  float acc[24];
#pragma unroll
  for (int i = 0; i < 16; ++i) acc[i] = bo[i];
#pragma unroll
  for (int i = 0; i < 8; ++i) acc[16 + i] = bw[i];
#pragma unroll
  for (int c = 0; c < C_; ++c) {
    const float v = fb[c * HW_ + hw];
#pragma unroll
    for (int i = 0; i < 16; ++i) acc[i] = fmaf(Wo[i * C_ + c], v, acc[i]);
#pragma unroll
    for (int i = 0; i < 8; ++i) acc[16 + i] = fmaf(Ww[i * C_ + c], v, acc[16 + i]);
  }
  float m = acc[16];
#pragma unroll
  for (int k = 1; k < K_; ++k) m = fmaxf(m, acc[16 + k]);
  float wt[K_];
  float s = 0.f;
#pragma unroll
  for (int k = 0; k < K_; ++k) { wt[k] = __expf(acc[16 + k] - m); s += wt[k]; }
  const float fm = (mask[p] != 0) ? 1.f : 0.f;
  const float inv = fm / s;
#pragma unroll
  for (int k = 0; k < K_; ++k) wt[k] *= inv;
  float res[C_];
#pragma unroll
  for (int c = 0; c < C_; ++c) res[c] = 0.f;
  if (fm != 0.f) {
#pragma unroll
    for (int k = 0; k < K_; ++k) {
      const float px = (float)x + acc[2 * k];
      const float py = (float)y + acc[2 * k + 1];
      const float x0f = floorf(px), y0f = floorf(py);
      const float wx = px - x0f, wy = py - y0f;
      const int x0 = (int)x0f, y0 = (int)y0f;
      const int x1 = x0 + 1, y1 = y0 + 1;
      const bool vx0 = ((unsigned)x0 < (unsigned)W_);
      const bool vx1 = ((unsigned)x1 < (unsigned)W_);
      const bool vy0 = ((unsigned)y0 < (unsigned)H_);
      const bool vy1 = ((unsigned)y1 < (unsigned)H_);
      const int cx0 = min(max(x0, 0), W_ - 1), cx1 = min(max(x1, 0), W_ - 1);
      const int cy0 = min(max(y0, 0), H_ - 1), cy1 = min(max(y1, 0), H_ - 1);
      const float wk = wt[k];
      const float w00 = wk * (1.f - wx) * (1.f - wy) * ((vx0 && vy0) ? 1.f : 0.f);
      const float w01 = wk * wx * (1.f - wy) * ((vx1 && vy0) ? 1.f : 0.f);
      const float w10 = wk * (1.f - wx) * wy * ((vx0 && vy1) ? 1.f : 0.f);
      const float w11 = wk * wx * wy * ((vx1 && vy1) ? 1.f : 0.f);
      const int i00 = cy0 * W_ + cx0, i01 = cy0 * W_ + cx1;
      const int i10 = cy1 * W_ + cx0, i11 = cy1 * W_ + cx1;
#pragma unroll
      for (int c = 0; c < C_; ++c) {
        const float* fc = fb + c * HW_;
        res[c] += w00 * fc[i00] + w01 * fc[i01] + w10 * fc[i10] + w11 * fc[i11];
      }
    }
  }
#pragma unroll
  for (int c = 0; c < C_; ++c)
    out[b * CHW_ + c * HW_ + hw] = fb[c * HW_ + hw] + res[c];
}

extern "C" void kernel_launch(void* const* d_in, const int* in_sizes, int n_in,
                              void* d_out, int out_size, void* d_ws, size_t ws_size,
                              hipStream_t stream) {
  const float* feat = (const float*)d_in[0];
  const int* mask = (const int*)d_in[1];
  const float* Wo = (const float*)d_in[2];
  const float* bo = (const float*)d_in[3];
  const float* Ww = (const float*)d_in[4];
  const float* bw = (const float*)d_in[5];
  float* out = (float*)d_out;

  if (ws_size >= WS_NEED_) {
    unsigned short* ft = (unsigned short*)d_ws;
    hipLaunchKernelGGL(transposeh_kernel, dim3(NBLK_), dim3(256), 0, stream,
                       feat, ft);
    hipLaunchKernelGGL(mega_kernel, dim3(NBLK_), dim3(256), 0, stream,
                       mask, Wo, bo, Ww, bw, ft, out);
  } else {
    hipLaunchKernelGGL(fused_kernel, dim3(NP_ / 256), dim3(256), 0, stream,
                       feat, mask, Wo, bo, Ww, bw, out);
  }
}